// Round 1
// baseline (31.206 us; speedup 1.0000x reference)
//
#include <hip/hip_runtime.h>
#include <hip/hip_bf16.h>

// StackedPyrHourGlassLoss — HIP implementation.
//
// Per level lvl:
//   patches over gt with shape pshape = PATCH_ORIG*dws, stride STRIDE[lvl]
//   center voxel at off = pshape//2 inside each patch
//   valid = (center != 0) && (on_bnd != 1) where on_bnd = max over 4 affinity
//           channels of (1 - aff) at the center (lvl0: channels 5..8 of tgt,
//           lvl>0: channels 1..4)
//   pp = sigmoid(emb @ W + b)  (emb = pred[:, center], 32 -> 1125)
//   per pooled output (5x15x15): trg = maxpool(gt_patch != center),
//           ign = maxpool(gt_patch == 0) > 0 ; ign zeroes pp and trg
//   dice accumulators: num += pp*trg, den += pp*pp + trg*trg (valid blocks only)
//   loss_lvl = -2*num/max(den, 1e-6);  total = sum over levels.
//
// Stage A: one workgroup per patch-block -> (num, den) partial pair in d_ws.
// Stage B: single-block finalize reduces the 3 levels and writes d_out[0].

constexpr int NBATCH = 2;
constexpr int EMB = 32;
constexpr int TGTC = 9;      // 1 gt + 8 affinity channels
constexpr int PZ = 5, PY = 15, PX = 15;
constexpr int P = PZ * PY * PX;   // 1125

// level block counts (N * nb0 * nb1 * nb2)
constexpr int NBLK0 = NBATCH * 4 * 17 * 17;  // 2312
constexpr int NBLK1 = NBATCH * 4 * 9 * 9;    // 648
constexpr int NBLK2 = NBATCH * 4 * 9 * 9;    // 648

template <int D, int H, int W,
          int NB0, int NBH, int NBW,
          int SH, int SW,
          int DH, int DWIN,
          int OFFZ, int OFFY, int OFFX,
          int AFFB>
__global__ __launch_bounds__(256)
void level_kernel(const float* __restrict__ pred,
                  const int* __restrict__ tgt,
                  const float* __restrict__ Wm,
                  const float* __restrict__ bv,
                  float* __restrict__ partials)
{
    const int gbid = blockIdx.x;
    const int tid  = threadIdx.x;

    // decompose block id -> (b, i, j, k); order irrelevant for the sum
    int k  = gbid % NBW;
    int t1 = gbid / NBW;
    int j  = t1 % NBH;
    int t2 = t1 / NBH;
    int i  = t2 % NB0;
    int b  = t2 / NB0;

    const int HW = H * W;
    const int CH = D * HW;             // elements per channel
    const int zc = OFFZ + i;           // stride along z is 1 for all levels
    const int yc = OFFY + j * SH;
    const int xc = OFFX + k * SW;
    const int cidx = zc * HW + yc * W + xc;

    __shared__ float s_emb[EMB];
    __shared__ int   s_c;
    __shared__ int   s_valid;

    if (tid == 0) {
        const int c = tgt[b * TGTC * CH + cidx];
        float onb = -1e30f;
        #pragma unroll
        for (int ch = 0; ch < 4; ++ch) {
            const int a = tgt[(b * TGTC + AFFB + ch) * CH + cidx];
            onb = fmaxf(onb, 1.0f - (float)a);
        }
        s_c = c;
        s_valid = (c != 0) && (onb != 1.0f);
    }
    __syncthreads();

    if (!s_valid) {
        if (tid == 0) {
            partials[2 * gbid]     = 0.0f;
            partials[2 * gbid + 1] = 0.0f;
        }
        return;
    }

    if (tid < EMB)
        s_emb[tid] = pred[(b * EMB + tid) * CH + cidx];
    __syncthreads();

    const int* __restrict__ gtb = tgt + b * TGTC * CH;  // channel 0 (gt)
    const int c = s_c;

    float num = 0.0f, den = 0.0f;
    for (int o = tid; o < P; o += blockDim.x) {
        const int pz = o / (PY * PX);
        const int r  = o - pz * (PY * PX);
        const int py = r / PX;
        const int px = r - py * PX;

        // 32 -> 1 dot product; W is (32, 1125) row-major, column o coalesced
        float dot = bv[o];
        #pragma unroll
        for (int e = 0; e < EMB; ++e)
            dot = fmaf(s_emb[e], Wm[e * P + o], dot);
        float pp = 1.0f / (1.0f + expf(-dot));

        // pooled window over the full-resolution patch
        const int zb = i + pz;                 // dws_z == 1 for all levels
        const int yb = j * SH + py * DH;
        const int xb = k * SW + px * DWIN;
        bool anyz = false, anyd = false;
        #pragma unroll
        for (int wy = 0; wy < DH; ++wy) {
            #pragma unroll
            for (int wx = 0; wx < DWIN; ++wx) {
                const int g = gtb[zb * HW + (yb + wy) * W + (xb + wx)];
                anyz |= (g == 0);
                anyd |= (g != c);
            }
        }
        float trg = (anyz || !anyd) ? 0.0f : 1.0f;
        if (anyz) pp = 0.0f;

        num = fmaf(pp, trg, num);
        den += pp * pp + trg * trg;
    }

    // block reduction: wave64 shuffle, then cross-wave via LDS
    #pragma unroll
    for (int off = 32; off > 0; off >>= 1) {
        num += __shfl_down(num, off);
        den += __shfl_down(den, off);
    }
    __shared__ float sn[4], sd[4];
    if ((tid & 63) == 0) { sn[tid >> 6] = num; sd[tid >> 6] = den; }
    __syncthreads();
    if (tid == 0) {
        partials[2 * gbid]     = sn[0] + sn[1] + sn[2] + sn[3];
        partials[2 * gbid + 1] = sd[0] + sd[1] + sd[2] + sd[3];
    }
}

__global__ __launch_bounds__(256)
void finalize_kernel(const float* __restrict__ partials, float* __restrict__ out)
{
    const int tid = threadIdx.x;
    const int counts[3] = { NBLK0, NBLK1, NBLK2 };
    const int offs[3]   = { 0, NBLK0, NBLK0 + NBLK1 };

    __shared__ float sn[4], sd[4];
    __shared__ float s_loss;
    if (tid == 0) s_loss = 0.0f;
    __syncthreads();

    for (int l = 0; l < 3; ++l) {
        float n = 0.0f, d = 0.0f;
        for (int p = tid; p < counts[l]; p += blockDim.x) {
            n += partials[2 * (offs[l] + p)];
            d += partials[2 * (offs[l] + p) + 1];
        }
        #pragma unroll
        for (int off = 32; off > 0; off >>= 1) {
            n += __shfl_down(n, off);
            d += __shfl_down(d, off);
        }
        if ((tid & 63) == 0) { sn[tid >> 6] = n; sd[tid >> 6] = d; }
        __syncthreads();
        if (tid == 0) {
            const float N_ = sn[0] + sn[1] + sn[2] + sn[3];
            const float D_ = sd[0] + sd[1] + sd[2] + sd[3];
            s_loss += -2.0f * N_ / fmaxf(D_, 1e-6f);
        }
        __syncthreads();
    }
    if (tid == 0) out[0] = s_loss;
}

extern "C" void kernel_launch(void* const* d_in, const int* in_sizes, int n_in,
                              void* d_out, int out_size, void* d_ws, size_t ws_size,
                              hipStream_t stream)
{
    // setup_inputs() dict order: pred0, tgt0, W0, b0, pred1, tgt1, W1, b1,
    //                            pred2, tgt2, W2, b2
    const float* pred0 = (const float*)d_in[0];
    const int*   tgt0  = (const int*)  d_in[1];
    const float* W0    = (const float*)d_in[2];
    const float* b0    = (const float*)d_in[3];
    const float* pred1 = (const float*)d_in[4];
    const int*   tgt1  = (const int*)  d_in[5];
    const float* W1    = (const float*)d_in[6];
    const float* b1    = (const float*)d_in[7];
    const float* pred2 = (const float*)d_in[8];
    const int*   tgt2  = (const int*)  d_in[9];
    const float* W2    = (const float*)d_in[10];
    const float* b2    = (const float*)d_in[11];

    float* out      = (float*)d_out;
    float* partials = (float*)d_ws;   // 2 floats per patch-block, 3608 pairs

    // lvl0: D,H,W=8,160,160  nb=(4,17,17) stride=(6,6) dws=(4,4) off=(2,30,30) aff ch 5..8
    level_kernel<8, 160, 160, 4, 17, 17, 6, 6, 4, 4, 2, 30, 30, 5>
        <<<NBLK0, 256, 0, stream>>>(pred0, tgt0, W0, b0, partials);
    // lvl1: 8,80,80  nb=(4,9,9) stride=(6,6) dws=(2,2) off=(2,15,15) aff ch 1..4
    level_kernel<8, 80, 80, 4, 9, 9, 6, 6, 2, 2, 2, 15, 15, 1>
        <<<NBLK1, 256, 0, stream>>>(pred1, tgt1, W1, b1, partials + 2 * NBLK0);
    // lvl2: 8,40,40  nb=(4,9,9) stride=(3,3) dws=(1,1) off=(2,7,7) aff ch 1..4
    level_kernel<8, 40, 40, 4, 9, 9, 3, 3, 1, 1, 2, 7, 7, 1>
        <<<NBLK2, 256, 0, stream>>>(pred2, tgt2, W2, b2, partials + 2 * (NBLK0 + NBLK1));

    finalize_kernel<<<1, 256, 0, stream>>>(partials, out);
}

// Round 2
// 20.491 us; speedup vs baseline: 1.5229x; 1.5229x over previous
//
#include <hip/hip_runtime.h>
#include <hip/hip_bf16.h>

// StackedPyrHourGlassLoss — HIP implementation, round 2.
// Fused: all three pyramid levels in ONE stage kernel (blockIdx range
// dispatch), then one finalize kernel. 2 graph nodes instead of 4.

constexpr int NBATCH = 2;
constexpr int EMB = 32;
constexpr int TGTC = 9;      // 1 gt + 8 affinity channels
constexpr int PZ = 5, PY = 15, PX = 15;
constexpr int P = PZ * PY * PX;   // 1125

constexpr int NBLK0 = NBATCH * 4 * 17 * 17;  // 2312
constexpr int NBLK1 = NBATCH * 4 * 9 * 9;    // 648
constexpr int NBLK2 = NBATCH * 4 * 9 * 9;    // 648
constexpr int NBLK_TOT = NBLK0 + NBLK1 + NBLK2;  // 3608

template <int D, int H, int W,
          int NB0, int NBH, int NBW,
          int SH, int SW,
          int DH, int DWIN,
          int OFFZ, int OFFY, int OFFX,
          int AFFB>
__device__ __forceinline__
void level_body(const int lbid,
                const float* __restrict__ pred,
                const int* __restrict__ tgt,
                const float* __restrict__ Wm,
                const float* __restrict__ bv,
                float* __restrict__ partials)
{
    const int tid = threadIdx.x;

    int k  = lbid % NBW;
    int t1 = lbid / NBW;
    int j  = t1 % NBH;
    int t2 = t1 / NBH;
    int i  = t2 % NB0;
    int b  = t2 / NB0;

    const int HW = H * W;
    const int CH = D * HW;
    const int zc = OFFZ + i;           // z-stride is 1 at all levels
    const int yc = OFFY + j * SH;
    const int xc = OFFX + k * SW;
    const int cidx = zc * HW + yc * W + xc;

    __shared__ float s_emb[EMB];
    __shared__ int   s_c;
    __shared__ int   s_valid;

    if (tid == 0) {
        const int c = tgt[b * TGTC * CH + cidx];
        bool allaff = true;
        #pragma unroll
        for (int ch = 0; ch < 4; ++ch)
            allaff &= (tgt[(b * TGTC + AFFB + ch) * CH + cidx] != 0);
        s_c = c;
        s_valid = (c != 0) && allaff;
    }
    __syncthreads();

    if (!s_valid) {
        if (tid == 0) {
            partials[2 * lbid]     = 0.0f;
            partials[2 * lbid + 1] = 0.0f;
        }
        return;
    }

    if (tid < EMB)
        s_emb[tid] = pred[(b * EMB + tid) * CH + cidx];
    __syncthreads();

    const int* __restrict__ gtb = tgt + b * TGTC * CH;  // gt channel
    const int c = s_c;

    float num = 0.0f, den = 0.0f;
    for (int o = tid; o < P; o += 256) {
        const int pz = o / (PY * PX);
        const int r  = o - pz * (PY * PX);
        const int py = r / PX;
        const int px = r - py * PX;

        float dot = bv[o];
        #pragma unroll
        for (int e = 0; e < EMB; ++e)
            dot = fmaf(s_emb[e], Wm[e * P + o], dot);
        float pp = 1.0f / (1.0f + expf(-dot));

        const int zb = i + pz;
        const int yb = j * SH + py * DH;
        const int xb = k * SW + px * DWIN;
        bool anyz = false, anyd = false;
        #pragma unroll
        for (int wy = 0; wy < DH; ++wy) {
            #pragma unroll
            for (int wx = 0; wx < DWIN; ++wx) {
                const int g = gtb[zb * HW + (yb + wy) * W + (xb + wx)];
                anyz |= (g == 0);
                anyd |= (g != c);
            }
        }
        float trg = (anyz || !anyd) ? 0.0f : 1.0f;
        if (anyz) pp = 0.0f;

        num = fmaf(pp, trg, num);
        den += pp * pp + trg * trg;
    }

    #pragma unroll
    for (int off = 32; off > 0; off >>= 1) {
        num += __shfl_down(num, off);
        den += __shfl_down(den, off);
    }
    __shared__ float sn[4], sd[4];
    if ((tid & 63) == 0) { sn[tid >> 6] = num; sd[tid >> 6] = den; }
    __syncthreads();
    if (tid == 0) {
        partials[2 * lbid]     = sn[0] + sn[1] + sn[2] + sn[3];
        partials[2 * lbid + 1] = sd[0] + sd[1] + sd[2] + sd[3];
    }
}

__global__ __launch_bounds__(256)
void stage_kernel(const float* __restrict__ pred0, const int* __restrict__ tgt0,
                  const float* __restrict__ W0, const float* __restrict__ b0,
                  const float* __restrict__ pred1, const int* __restrict__ tgt1,
                  const float* __restrict__ W1, const float* __restrict__ b1,
                  const float* __restrict__ pred2, const int* __restrict__ tgt2,
                  const float* __restrict__ W2, const float* __restrict__ b2,
                  float* __restrict__ partials)
{
    const int gb = blockIdx.x;
    if (gb < NBLK0) {
        // lvl0: 8,160,160  nb=(4,17,17) stride=6 dws=4 off=(2,30,30) aff 5..8
        level_body<8, 160, 160, 4, 17, 17, 6, 6, 4, 4, 2, 30, 30, 5>(
            gb, pred0, tgt0, W0, b0, partials);
    } else if (gb < NBLK0 + NBLK1) {
        // lvl1: 8,80,80  nb=(4,9,9) stride=6 dws=2 off=(2,15,15) aff 1..4
        level_body<8, 80, 80, 4, 9, 9, 6, 6, 2, 2, 2, 15, 15, 1>(
            gb - NBLK0, pred1, tgt1, W1, b1, partials + 2 * NBLK0);
    } else {
        // lvl2: 8,40,40  nb=(4,9,9) stride=3 dws=1 off=(2,7,7) aff 1..4
        level_body<8, 40, 40, 4, 9, 9, 3, 3, 1, 1, 2, 7, 7, 1>(
            gb - NBLK0 - NBLK1, pred2, tgt2, W2, b2,
            partials + 2 * (NBLK0 + NBLK1));
    }
}

__global__ __launch_bounds__(256)
void finalize_kernel(const float* __restrict__ partials, float* __restrict__ out)
{
    const int tid = threadIdx.x;
    const int counts[3] = { NBLK0, NBLK1, NBLK2 };
    const int offs[3]   = { 0, NBLK0, NBLK0 + NBLK1 };

    __shared__ float sn[4], sd[4];
    __shared__ float s_loss;
    if (tid == 0) s_loss = 0.0f;
    __syncthreads();

    for (int l = 0; l < 3; ++l) {
        float n = 0.0f, d = 0.0f;
        const float2* p2 = (const float2*)(partials + 2 * offs[l]);
        for (int p = tid; p < counts[l]; p += 256) {
            const float2 v = p2[p];
            n += v.x;
            d += v.y;
        }
        #pragma unroll
        for (int off = 32; off > 0; off >>= 1) {
            n += __shfl_down(n, off);
            d += __shfl_down(d, off);
        }
        if ((tid & 63) == 0) { sn[tid >> 6] = n; sd[tid >> 6] = d; }
        __syncthreads();
        if (tid == 0) {
            const float N_ = sn[0] + sn[1] + sn[2] + sn[3];
            const float D_ = sd[0] + sd[1] + sd[2] + sd[3];
            s_loss += -2.0f * N_ / fmaxf(D_, 1e-6f);
        }
        __syncthreads();
    }
    if (tid == 0) out[0] = s_loss;
}

extern "C" void kernel_launch(void* const* d_in, const int* in_sizes, int n_in,
                              void* d_out, int out_size, void* d_ws, size_t ws_size,
                              hipStream_t stream)
{
    const float* pred0 = (const float*)d_in[0];
    const int*   tgt0  = (const int*)  d_in[1];
    const float* W0    = (const float*)d_in[2];
    const float* b0    = (const float*)d_in[3];
    const float* pred1 = (const float*)d_in[4];
    const int*   tgt1  = (const int*)  d_in[5];
    const float* W1    = (const float*)d_in[6];
    const float* b1    = (const float*)d_in[7];
    const float* pred2 = (const float*)d_in[8];
    const int*   tgt2  = (const int*)  d_in[9];
    const float* W2    = (const float*)d_in[10];
    const float* b2    = (const float*)d_in[11];

    float* out      = (float*)d_out;
    float* partials = (float*)d_ws;   // 3608 (num,den) pairs

    stage_kernel<<<NBLK_TOT, 256, 0, stream>>>(
        pred0, tgt0, W0, b0, pred1, tgt1, W1, b1, pred2, tgt2, W2, b2,
        partials);
    finalize_kernel<<<1, 256, 0, stream>>>(partials, out);
}